// Round 5
// baseline (130.290 us; speedup 1.0000x reference)
//
#include <hip/hip_runtime.h>
#include <math.h>

#define NROWS 32768
#define DIM   64
#define NCODE 4096
#define EPS_RMS 1.1920929e-07f
#define EPS_BN  1e-5f

typedef _Float16 f16x8 __attribute__((ext_vector_type(8)));
typedef float    f32x4 __attribute__((ext_vector_type(4)));

// ws byte layout
#define WS_PS   0                        // partial sums   [64][64] f32
#define WS_PQ   16384                    // partial sumsq  [64][64] f32
#define WS_CC   32768                    // ccn[4096] = -0.5*sum(c^2)
#define WS_CB32 49152                    // cb fp32 [4096][64]
#define WS_CH   (49152 + 1048576)        // cb f16 hi [4096][64]
#define WS_CL   (WS_CH + 524288)         // cb f16 lo [4096][64]

// out float offsets
#define OUT1 ((size_t)NROWS * DIM)           // z_e
#define OUT2 ((size_t)2 * NROWS * DIM)       // q
#define OUT3 (OUT2 + NROWS)                  // z_q

#define MFMA16(a, b, c) __builtin_amdgcn_mfma_f32_16x16x32_f16(a, b, c, 0, 0, 0)

__device__ __forceinline__ void async_copy16(void* lds, const void* g) {
    __builtin_amdgcn_global_load_lds(
        (const __attribute__((address_space(1))) unsigned int*)g,
        (__attribute__((address_space(3))) unsigned int*)lds, 16, 0, 0);
}

__global__ __launch_bounds__(256) void k_bn1(const float* __restrict__ w,
                                             char* __restrict__ wsb) {
    __shared__ float s1[4][64], s2[4][64];
    int lane = threadIdx.x & 63, v = threadIdx.x >> 6;
    long base = (long)blockIdx.x * 64 + v * 16;
    float s = 0.f, sq = 0.f;
    #pragma unroll
    for (int i = 0; i < 16; i++) {
        float x = w[(base + i) * DIM + lane];
        s += x; sq += x * x;
    }
    s1[v][lane] = s; s2[v][lane] = sq;
    __syncthreads();
    if (threadIdx.x < 64) {
        float ts = s1[0][lane] + s1[1][lane] + s1[2][lane] + s1[3][lane];
        float tq = s2[0][lane] + s2[1][lane] + s2[2][lane] + s2[3][lane];
        ((float*)(wsb + WS_PS))[blockIdx.x * 64 + lane] = ts;
        ((float*)(wsb + WS_PQ))[blockIdx.x * 64 + lane] = tq;
    }
}

__global__ __launch_bounds__(256) void k_cb(const float* __restrict__ w,
                                            const float* __restrict__ bnw,
                                            const float* __restrict__ bnb,
                                            char* __restrict__ wsb) {
    __shared__ float s1[4][64], s2[4][64], af[64], bf[64];
    int t = threadIdx.x, lane = t & 63, v = t >> 6;
    const float* ps = (const float*)(wsb + WS_PS);
    const float* pq = (const float*)(wsb + WS_PQ);
    float s = 0.f, sq = 0.f;
    #pragma unroll
    for (int b = 0; b < 16; b++) {
        s  += ps[(v * 16 + b) * 64 + lane];
        sq += pq[(v * 16 + b) * 64 + lane];
    }
    s1[v][lane] = s; s2[v][lane] = sq;
    __syncthreads();
    if (t < 64) {
        float ts = s1[0][lane] + s1[1][lane] + s1[2][lane] + s1[3][lane];
        float tq = s2[0][lane] + s2[1][lane] + s2[2][lane] + s2[3][lane];
        float mean = ts * (1.0f / NCODE);
        float var  = tq * (1.0f / NCODE) - mean * mean;
        float a = rsqrtf(var + EPS_BN) * bnw[lane];
        af[lane] = a;
        bf[lane] = bnb[lane] - mean * a;
    }
    __syncthreads();
    float a = af[lane], bb = bf[lane];
    float*     cb32 = (float*)(wsb + WS_CB32);
    _Float16*  chG  = (_Float16*)(wsb + WS_CH);
    _Float16*  clG  = (_Float16*)(wsb + WS_CL);
    float*     ccp  = (float*)(wsb + WS_CC);
    #pragma unroll
    for (int i = 0; i < 4; i++) {
        long row = (long)blockIdx.x * 16 + v * 4 + i;
        float x = w[row * DIM + lane];
        float h = fmaf(x, a, bb);
        float ss = h * h;
        #pragma unroll
        for (int m = 1; m < 64; m <<= 1) ss += __shfl_xor(ss, m);
        float rms = rsqrtf(ss * (1.0f / DIM) + EPS_RMS);
        float c = h * rms;
        cb32[row * DIM + lane] = c;
        _Float16 ch = (_Float16)c;
        chG[row * DIM + lane] = ch;
        clG[row * DIM + lane] = (_Float16)(c - (float)ch);
        float cs = c * c;
        #pragma unroll
        for (int m = 1; m < 64; m <<= 1) cs += __shfl_xor(cs, m);
        if (lane == 0) ccp[row] = -0.5f * cs;   // folded into MFMA C-init
    }
}

// ---- main: 512 thr / 8 waves, 64 rows/block, 64-code tiles (64 passes)
//      LDS 32KB -> 3 blocks/CU resident: cross-block overlap hides phase bubbles
__global__ __launch_bounds__(512, 6) void k_main(const float* __restrict__ z,
                                                 const char* __restrict__ wsb,
                                                 float* __restrict__ out) {
    // buf0 @0 (hi 8K @0, lo 8K @8192), buf1 @16384; z prologue overlays buf1
    __shared__ __align__(16) unsigned char sm[32768];

    const int tid  = threadIdx.x;
    const int lane = tid & 63;
    const int w    = tid >> 6;      // 0..7
    const int wr   = w >> 2;        // row half (32 rows)
    const int wc   = w & 3;         // code quarter (16 codes/pass)
    const int l15  = lane & 15;
    const int l4   = lane >> 4;
    const long rowbase = (long)blockIdx.x * 64;

    const _Float16* chG  = (const _Float16*)(wsb + WS_CH);
    const _Float16* clG  = (const _Float16*)(wsb + WS_CL);
    const float*    ccnG = (const float*)(wsb + WS_CC);
    const float*    cb32 = (const float*)(wsb + WS_CB32);

    // staging: 1 load/thread/matrix; LDS dest wave-uniform base (HW adds lane*16),
    // global src per-lane inverse-XOR-swizzled
    const int B0    = w * 1024 + lane * 16;        // linear tile byte (8KB tile)
    const int scode = B0 >> 7;                     // 0..63
    const int ssp   = (B0 >> 4) & 7;
    const long gsw  = (long)scode * DIM + (long)((ssp ^ (scode & 7)) * 8);

    // ---- stage pass 0 into buf0 (overlaps z prologue)
    async_copy16(sm + w * 1024,        chG + gsw);
    async_copy16(sm + 8192 + w * 1024, clG + gsw);

    // ---- prologue: RMS-norm 64 rows of z, write z_e, split hi/lo into buf1
    {
        int r = tid >> 3, seg = tid & 7;   // 8 floats per thread
        const float* zrow = z + (rowbase + r) * DIM + seg * 8;
        float vv[8];
        float ss = 0.f;
        #pragma unroll
        for (int i = 0; i < 8; i++) { vv[i] = zrow[i]; ss += vv[i] * vv[i]; }
        ss += __shfl_xor(ss, 1);
        ss += __shfl_xor(ss, 2);
        ss += __shfl_xor(ss, 4);
        float rms = rsqrtf(ss * (1.0f / DIM) + EPS_RMS);
        float* oz = out + OUT1 + (rowbase + r) * DIM + seg * 8;
        __align__(16) _Float16 hb[8], lb[8];
        #pragma unroll
        for (int i = 0; i < 8; i++) {
            float x = vv[i] * rms;
            oz[i] = x;
            _Float16 h = (_Float16)x;
            hb[i] = h;
            lb[i] = (_Float16)(x - (float)h);
        }
        *(f16x8*)(sm + 16384 + r * 128 + seg * 16) = *(f16x8*)hb;
        *(f16x8*)(sm + 24576 + r * 128 + seg * 16) = *(f16x8*)lb;
    }
    __syncthreads();

    // ---- A fragments (z) to registers: 2 row-subtiles x 2 k-chunks, hi+lo
    f16x8 ah[2][2], al[2][2];
    #pragma unroll
    for (int s = 0; s < 2; s++)
        #pragma unroll
        for (int c = 0; c < 2; c++) {
            int arow = wr * 32 + s * 16 + l15;
            ah[s][c] = *(const f16x8*)(sm + 16384 + arow * 128 + c * 64 + l4 * 16);
            al[s][c] = *(const f16x8*)(sm + 24576 + arow * 128 + c * 64 + l4 * 16);
        }
    __syncthreads();   // buf1 free for staging from here

    // B-fragment LDS offsets (pass-invariant, XOR-swizzled)
    int boff[2];
    {
        int coderow = wc * 16 + l15;   // 0..63
        #pragma unroll
        for (int c = 0; c < 2; c++)
            boff[c] = coderow * 128 + ((c * 64 + l4 * 16) ^ ((coderow & 7) << 4));
    }
    const int codeoff = wc * 16 + l15;   // + p*64

    float ccv = ccnG[codeoff];

    float bmax[2][4];
    int   bix[2][4];
    #pragma unroll
    for (int s = 0; s < 2; s++)
        #pragma unroll
        for (int r = 0; r < 4; r++) { bmax[s][r] = -3.4e38f; bix[s][r] = 0; }

    #define COMPUTE_PASS(p)                                                        \
    {                                                                              \
        const unsigned char* chT = sm + ((p) & 1) * 16384;                         \
        const unsigned char* clT = chT + 8192;                                     \
        f16x8 bh[2], bl[2];                                                        \
        _Pragma("unroll")                                                          \
        for (int c = 0; c < 2; c++) {                                              \
            bh[c] = *(const f16x8*)(chT + boff[c]);                                \
            bl[c] = *(const f16x8*)(clT + boff[c]);                                \
        }                                                                          \
        int code = (p) * 64 + codeoff;                                             \
        _Pragma("unroll")                                                          \
        for (int s = 0; s < 2; s++) {                                              \
            f32x4 a2 = {ccv, ccv, ccv, ccv};                                       \
            a2 = MFMA16(ah[s][0], bh[0], a2);                                      \
            a2 = MFMA16(ah[s][1], bh[1], a2);                                      \
            a2 = MFMA16(ah[s][0], bl[0], a2);                                      \
            a2 = MFMA16(ah[s][1], bl[1], a2);                                      \
            a2 = MFMA16(al[s][0], bh[0], a2);                                      \
            a2 = MFMA16(al[s][1], bh[1], a2);                                      \
            _Pragma("unroll")                                                      \
            for (int r = 0; r < 4; r++) {                                          \
                if (a2[r] > bmax[s][r]) { bmax[s][r] = a2[r]; bix[s][r] = code; }  \
            }                                                                      \
        }                                                                          \
    }

    const _Float16* ghp = chG + gsw + 4096;   // pass 1 tile (64 codes * 64 d)
    const _Float16* glp = clG + gsw + 4096;
    const float*    cnp = ccnG + 64 + codeoff;

    for (int p = 0; p < 63; ++p) {
        // stage pass p+1 into the other buffer (flies under this pass's compute)
        unsigned char* nb = sm + ((p + 1) & 1) * 16384;
        async_copy16(nb + w * 1024,        ghp);
        async_copy16(nb + 8192 + w * 1024, glp);
        ghp += 4096; glp += 4096;
        float ccn_nx = *cnp;
        cnp += 64;

        COMPUTE_PASS(p);

        __syncthreads();   // drains staging; closes reads of current buffer
        ccv = ccn_nx;
    }
    COMPUTE_PASS(63);

    // ---- argmax reduce: 16 code-lanes, then the 4 code-quarter waves
    float* redd = (float*)sm;            // [64][4]
    int*   redi = (int*)(sm + 1024);     // [64][4]
    int*   bidx = (int*)(sm + 2048);     // [64]
    #pragma unroll
    for (int s = 0; s < 2; s++)
        #pragma unroll
        for (int r = 0; r < 4; r++) {
            float d = bmax[s][r];
            int   ix = bix[s][r];
            #pragma unroll
            for (int m = 1; m < 16; m <<= 1) {
                float od = __shfl_xor(d, m);
                int   oi = __shfl_xor(ix, m);
                if (od > d || (od == d && oi < ix)) { d = od; ix = oi; }
            }
            if (l15 == 0) {
                int rowloc = wr * 32 + s * 16 + l4 * 4 + r;
                redd[rowloc * 4 + wc] = d;
                redi[rowloc * 4 + wc] = ix;
            }
        }
    __syncthreads();
    if (tid < 64) {
        float bv = redd[tid * 4];
        int   bi_ = redi[tid * 4];
        #pragma unroll
        for (int j = 1; j < 4; j++) {
            float dj = redd[tid * 4 + j];
            int   ij = redi[tid * 4 + j];
            if (dj > bv || (dj == bv && ij < bi_)) { bv = dj; bi_ = ij; }
        }
        bidx[tid] = bi_;
        out[OUT2 + rowbase + tid] = (float)bi_;
    }
    __syncthreads();
    {   // gather cb32[best] -> chunk0 and chunk3
        int r = tid >> 3, seg = tid & 7;
        int ix = bidx[r];
        const float* src = cb32 + (long)ix * DIM + seg * 8;
        float* o0 = out + (rowbase + r) * DIM + seg * 8;
        float* o3 = out + OUT3 + (rowbase + r) * DIM + seg * 8;
        #pragma unroll
        for (int i = 0; i < 8; i++) { float t = src[i]; o0[i] = t; o3[i] = t; }
    }
}

extern "C" void kernel_launch(void* const* d_in, const int* in_sizes, int n_in,
                              void* d_out, int out_size, void* d_ws, size_t ws_size,
                              hipStream_t stream) {
    const float* z   = (const float*)d_in[0];
    const float* w   = (const float*)d_in[1];
    const float* bnw = (const float*)d_in[2];
    const float* bnb = (const float*)d_in[3];
    float* out = (float*)d_out;
    char*  wsb = (char*)d_ws;

    k_bn1 <<<64,  256, 0, stream>>>(w, wsb);
    k_cb  <<<256, 256, 0, stream>>>(w, bnw, bnb, wsb);
    k_main<<<512, 512, 0, stream>>>(z, wsb, out);
}

// Round 6
// 70.215 us; speedup vs baseline: 1.8556x; 1.8556x over previous
//
#include <hip/hip_runtime.h>
#include <math.h>

#define NROWS 32768
#define DIM   64
#define NCODE 4096
#define EPS_RMS 1.1920929e-07f
#define EPS_BN  1e-5f

typedef _Float16 f16x8 __attribute__((ext_vector_type(8)));
typedef float    f32x4 __attribute__((ext_vector_type(4)));

// ws byte layout
#define WS_PS   0                          // partial sums  [64][64] f32
#define WS_PQ   16384                      // partial sumsq [64][64] f32
#define WS_CC   32768                      // ccn[4096] = -0.5*sum(c^2)
#define WS_CB32 49152                      // cb fp32 [4096][64] (for gather)
#define WS_PH   (49152 + 1048576)          // packed B-frag hi [256 grp][2 c][64 lane][16B]
#define WS_PL   (WS_PH + 524288)           // packed B-frag lo

// out float offsets
#define OUT1 ((size_t)NROWS * DIM)           // z_e
#define OUT2 ((size_t)2 * NROWS * DIM)       // q
#define OUT3 (OUT2 + NROWS)                  // z_q

#define MFMA16(a, b, c) __builtin_amdgcn_mfma_f32_16x16x32_f16(a, b, c, 0, 0, 0)

__global__ __launch_bounds__(256) void k_bn1(const float* __restrict__ w,
                                             char* __restrict__ wsb) {
    __shared__ float s1[4][64], s2[4][64];
    int lane = threadIdx.x & 63, v = threadIdx.x >> 6;
    long base = (long)blockIdx.x * 64 + v * 16;
    float s = 0.f, sq = 0.f;
    #pragma unroll
    for (int i = 0; i < 16; i++) {
        float x = w[(base + i) * DIM + lane];
        s += x; sq += x * x;
    }
    s1[v][lane] = s; s2[v][lane] = sq;
    __syncthreads();
    if (threadIdx.x < 64) {
        float ts = s1[0][lane] + s1[1][lane] + s1[2][lane] + s1[3][lane];
        float tq = s2[0][lane] + s2[1][lane] + s2[2][lane] + s2[3][lane];
        ((float*)(wsb + WS_PS))[blockIdx.x * 64 + lane] = ts;
        ((float*)(wsb + WS_PQ))[blockIdx.x * 64 + lane] = tq;
    }
}

// one block = one 16-code group g: normalize, write cb32/ccn, emit packed B-frags
__global__ __launch_bounds__(256) void k_cb(const float* __restrict__ w,
                                            const float* __restrict__ bnw,
                                            const float* __restrict__ bnb,
                                            char* __restrict__ wsb) {
    __shared__ float s1[4][64], s2[4][64], af[64], bf[64];
    __shared__ _Float16 sh[16][64], sl[16][64];
    int t = threadIdx.x, lane = t & 63, v = t >> 6;
    const float* ps = (const float*)(wsb + WS_PS);
    const float* pq = (const float*)(wsb + WS_PQ);
    float s = 0.f, sq = 0.f;
    #pragma unroll
    for (int b = 0; b < 16; b++) {
        s  += ps[(v * 16 + b) * 64 + lane];
        sq += pq[(v * 16 + b) * 64 + lane];
    }
    s1[v][lane] = s; s2[v][lane] = sq;
    __syncthreads();
    if (t < 64) {
        float ts = s1[0][lane] + s1[1][lane] + s1[2][lane] + s1[3][lane];
        float tq = s2[0][lane] + s2[1][lane] + s2[2][lane] + s2[3][lane];
        float mean = ts * (1.0f / NCODE);
        float var  = tq * (1.0f / NCODE) - mean * mean;
        float a = rsqrtf(var + EPS_BN) * bnw[lane];
        af[lane] = a;
        bf[lane] = bnb[lane] - mean * a;
    }
    __syncthreads();
    float a = af[lane], bb = bf[lane];
    float* cb32 = (float*)(wsb + WS_CB32);
    float* ccp  = (float*)(wsb + WS_CC);
    int g = blockIdx.x;
    #pragma unroll
    for (int i = 0; i < 4; i++) {
        int  rl  = v * 4 + i;            // 0..15 within group
        long row = (long)g * 16 + rl;
        float x = w[row * DIM + lane];
        float h = fmaf(x, a, bb);
        float ss = h * h;
        #pragma unroll
        for (int m = 1; m < 64; m <<= 1) ss += __shfl_xor(ss, m);
        float rms = rsqrtf(ss * (1.0f / DIM) + EPS_RMS);
        float c = h * rms;
        cb32[row * DIM + lane] = c;
        _Float16 ch = (_Float16)c;
        sh[rl][lane] = ch;
        sl[rl][lane] = (_Float16)(c - (float)ch);
        float cs = c * c;
        #pragma unroll
        for (int m = 1; m < 64; m <<= 1) cs += __shfl_xor(cs, m);
        if (lane == 0) ccp[row] = -0.5f * cs;   // folded into MFMA C-init
    }
    __syncthreads();
    // packed B-frag emit: t>>7 = matrix (0 hi, 1 lo), u=t&127: c=u>>6, l=u&63
    {
        int u = t & 127;
        int c = u >> 6, l = u & 63;
        int codel = l & 15;
        int kbase = c * 32 + (l >> 4) * 8;
        size_t dst = (size_t)((g * 2 + c) * 64 + l) * 16;
        if (t < 128) {
            *(f16x8*)(wsb + WS_PH + dst) = *(const f16x8*)&sh[codel][kbase];
        } else {
            *(f16x8*)(wsb + WS_PL + dst) = *(const f16x8*)&sl[codel][kbase];
        }
    }
}

// ---- main: 256 thr / 4 waves, 64 rows/block; each wave: all 64 rows (A in regs),
//      scans a contiguous 1024-code quarter from L2. NO barriers in main loop.
__global__ __launch_bounds__(256, 3) void k_main(const float* __restrict__ z,
                                                 const char* __restrict__ wsb,
                                                 float* __restrict__ out) {
    __shared__ __align__(16) unsigned char sm[18688];
    // zh f16[64][64] @0 (8KB), zl @8192; reduce: redd@16384, redi@17408, bidx@18432

    const int tid  = threadIdx.x;
    const int lane = tid & 63;
    const int w    = tid >> 6;      // wave 0..3 = code quarter
    const int l15  = lane & 15;
    const int l4   = lane >> 4;
    const long rowbase = (long)blockIdx.x * 64;

    const float* ccnG = (const float*)(wsb + WS_CC);
    const float* cb32 = (const float*)(wsb + WS_CB32);

    // ---- prologue: RMS-norm 64 rows of z, write z_e, hi/lo split into LDS
    {
        int r = tid >> 2, seg = tid & 3;   // 16 floats per thread
        const float4* zp = (const float4*)(z + (rowbase + r) * DIM + seg * 16);
        float4 v4[4];
        float ss = 0.f;
        #pragma unroll
        for (int i = 0; i < 4; i++) {
            v4[i] = zp[i];
            ss += v4[i].x * v4[i].x + v4[i].y * v4[i].y + v4[i].z * v4[i].z + v4[i].w * v4[i].w;
        }
        ss += __shfl_xor(ss, 1);
        ss += __shfl_xor(ss, 2);
        float rms = rsqrtf(ss * (1.0f / DIM) + EPS_RMS);
        float4* oz = (float4*)(out + OUT1 + (rowbase + r) * DIM + seg * 16);
        __align__(16) _Float16 hb[16], lb[16];
        #pragma unroll
        for (int i = 0; i < 4; i++) {
            float xs[4] = {v4[i].x, v4[i].y, v4[i].z, v4[i].w};
            #pragma unroll
            for (int j = 0; j < 4; j++) {
                float x = xs[j] * rms;
                _Float16 h = (_Float16)x;
                hb[i * 4 + j] = h;
                lb[i * 4 + j] = (_Float16)(x - (float)h);
                xs[j] = x;
            }
            oz[i] = make_float4(xs[0], xs[1], xs[2], xs[3]);
        }
        unsigned char* zhp = sm + r * 128 + seg * 32;
        ((f16x8*)zhp)[0] = ((f16x8*)hb)[0];
        ((f16x8*)zhp)[1] = ((f16x8*)hb)[1];
        unsigned char* zlp = zhp + 8192;
        ((f16x8*)zlp)[0] = ((f16x8*)lb)[0];
        ((f16x8*)zlp)[1] = ((f16x8*)lb)[1];
    }
    __syncthreads();

    // ---- A fragments: 4 row-subtiles x 2 k-chunks, hi+lo (64 VGPR)
    f16x8 ah[4][2], al[4][2];
    #pragma unroll
    for (int s = 0; s < 4; s++)
        #pragma unroll
        for (int c = 0; c < 2; c++) {
            int off = (s * 16 + l15) * 128 + c * 64 + l4 * 16;
            ah[s][c] = *(const f16x8*)(sm + off);
            al[s][c] = *(const f16x8*)(sm + 8192 + off);
        }

    float bmax[4][4];
    int   bix[4][4];
    #pragma unroll
    for (int s = 0; s < 4; s++)
        #pragma unroll
        for (int r = 0; r < 4; r++) { bmax[s][r] = -3.4e38f; bix[s][r] = 0; }

    // B-stream: wave w scans groups gw..gw+63 (contiguous 1024 codes)
    const int gw = w * 64;
    const char* pH = wsb + WS_PH + (size_t)(gw * 2) * 1024 + lane * 16;
    const char* pL = wsb + WS_PL + (size_t)(gw * 2) * 1024 + lane * 16;
    const float* cn = ccnG + gw * 16 + l15;

    #define LOADB(H0, H1, L0, L1, CC, k)                       \
        H0 = *(const f16x8*)(pH + (size_t)(k) * 2048);         \
        H1 = *(const f16x8*)(pH + (size_t)(k) * 2048 + 1024);  \
        L0 = *(const f16x8*)(pL + (size_t)(k) * 2048);         \
        L1 = *(const f16x8*)(pL + (size_t)(k) * 2048 + 1024);  \
        CC = cn[(k) * 16];

    #define COMPUTE(H0, H1, L0, L1, CC, k)                                        \
    {                                                                             \
        int code = (gw + (k)) * 16 + l15;                                         \
        _Pragma("unroll")                                                         \
        for (int s = 0; s < 4; s++) {                                             \
            f32x4 a2 = {CC, CC, CC, CC};                                          \
            a2 = MFMA16(ah[s][0], H0, a2);                                        \
            a2 = MFMA16(ah[s][1], H1, a2);                                        \
            a2 = MFMA16(ah[s][0], L0, a2);                                        \
            a2 = MFMA16(ah[s][1], L1, a2);                                        \
            a2 = MFMA16(al[s][0], H0, a2);                                        \
            a2 = MFMA16(al[s][1], H1, a2);                                        \
            _Pragma("unroll")                                                     \
            for (int r = 0; r < 4; r++) {                                         \
                if (a2[r] > bmax[s][r]) { bmax[s][r] = a2[r]; bix[s][r] = code; } \
            }                                                                     \
        }                                                                         \
    }

    f16x8 hA0, hA1, lA0, lA1, hB0, hB1, lB0, lB1;
    float ccA, ccB;
    LOADB(hA0, hA1, lA0, lA1, ccA, 0);
    #pragma unroll 1
    for (int k = 0; k < 62; k += 2) {
        LOADB(hB0, hB1, lB0, lB1, ccB, k + 1);
        COMPUTE(hA0, hA1, lA0, lA1, ccA, k);
        LOADB(hA0, hA1, lA0, lA1, ccA, k + 2);
        COMPUTE(hB0, hB1, lB0, lB1, ccB, k + 1);
    }
    LOADB(hB0, hB1, lB0, lB1, ccB, 63);
    COMPUTE(hA0, hA1, lA0, lA1, ccA, 62);
    COMPUTE(hB0, hB1, lB0, lB1, ccB, 63);

    // ---- argmax reduce: 16 code-lanes, then the 4 waves
    float* redd = (float*)(sm + 16384);   // [64][4]
    int*   redi = (int*)(sm + 17408);     // [64][4]
    int*   bidx = (int*)(sm + 18432);     // [64]
    #pragma unroll
    for (int s = 0; s < 4; s++)
        #pragma unroll
        for (int r = 0; r < 4; r++) {
            float d = bmax[s][r];
            int   ix = bix[s][r];
            #pragma unroll
            for (int m = 1; m < 16; m <<= 1) {
                float od = __shfl_xor(d, m);
                int   oi = __shfl_xor(ix, m);
                if (od > d || (od == d && oi < ix)) { d = od; ix = oi; }
            }
            if (l15 == 0) {
                int row = s * 16 + l4 * 4 + r;
                redd[row * 4 + w] = d;
                redi[row * 4 + w] = ix;
            }
        }
    __syncthreads();
    if (tid < 64) {
        float bv = redd[tid * 4];
        int   bi_ = redi[tid * 4];
        #pragma unroll
        for (int j = 1; j < 4; j++) {
            float dj = redd[tid * 4 + j];
            int   ij = redi[tid * 4 + j];
            if (dj > bv || (dj == bv && ij < bi_)) { bv = dj; bi_ = ij; }
        }
        bidx[tid] = bi_;
        out[OUT2 + rowbase + tid] = (float)bi_;
    }
    __syncthreads();
    {   // gather cb32[best] -> chunk0 and chunk3
        int r = tid >> 2, seg = tid & 3;
        int ix = bidx[r];
        const float4* src = (const float4*)(cb32 + (long)ix * DIM + seg * 16);
        float4* o0 = (float4*)(out + (rowbase + r) * DIM + seg * 16);
        float4* o3 = (float4*)(out + OUT3 + (rowbase + r) * DIM + seg * 16);
        #pragma unroll
        for (int i = 0; i < 4; i++) { float4 t4 = src[i]; o0[i] = t4; o3[i] = t4; }
    }
}

extern "C" void kernel_launch(void* const* d_in, const int* in_sizes, int n_in,
                              void* d_out, int out_size, void* d_ws, size_t ws_size,
                              hipStream_t stream) {
    const float* z   = (const float*)d_in[0];
    const float* w   = (const float*)d_in[1];
    const float* bnw = (const float*)d_in[2];
    const float* bnb = (const float*)d_in[3];
    float* out = (float*)d_out;
    char*  wsb = (char*)d_ws;

    k_bn1 <<<64,  256, 0, stream>>>(w, wsb);
    k_cb  <<<256, 256, 0, stream>>>(w, bnw, bnb, wsb);
    k_main<<<512, 256, 0, stream>>>(z, wsb, out);
}